// Round 1
// baseline (342.854 us; speedup 1.0000x reference)
//
#include <hip/hip_runtime.h>
#include <stdint.h>
#include <math.h>

#define NUM_CLASSES 21
#define TOPK 200
#define P_NUM 120000
#define B_NUM 8
#define NBINS 4096
#define CAP 2048
#define PRE_TH 0.99f
#define TSAFE 4060            // bins >= TSAFE guarantee score > PRE_TH (4060/4096 ≈ 0.99121)
#define CONF_TH 0.05f
#define NMS_TH 0.3f
#define TROWS 512             // rows per transpose block

// ---------------------------------------------------------------------------
// Kernel 1: transpose conf [B*P, C] -> confT [B][C][P] for coalesced scans
// ---------------------------------------------------------------------------
__global__ __launch_bounds__(256) void transpose_kernel(const float* __restrict__ conf,
                                                        float* __restrict__ confT) {
    __shared__ float tile[TROWS * NUM_CLASSES];   // 512*21*4 = 43008 B
    const int r0 = blockIdx.x * TROWS;
    const int t  = threadIdx.x;
    const long long base = (long long)r0 * NUM_CLASSES;
    // coalesced load: 512*21 = 10752 = 42 * 256
    #pragma unroll
    for (int i = 0; i < (TROWS * NUM_CLASSES) / 256; ++i) {
        int idx = t + i * 256;
        tile[idx] = conf[base + idx];
    }
    __syncthreads();
    // coalesced store per class
    for (int c = 0; c < NUM_CLASSES; ++c) {
        #pragma unroll
        for (int h = 0; h < TROWS / 256; ++h) {
            int l = h * 256 + t;
            int r = r0 + l;
            int b = r / P_NUM;
            int p = r - b * P_NUM;
            confT[((long long)(b * NUM_CLASSES + c)) * P_NUM + p] = tile[l * NUM_CLASSES + c];
        }
    }
}

// ---------------------------------------------------------------------------
// Kernel 2: per-(b,c) exact top-200 selection + greedy NMS
// ---------------------------------------------------------------------------
__global__ __launch_bounds__(256) void select_nms_kernel(
        const float* __restrict__ conf,       // [B*P, C] original layout
        const float* __restrict__ loc,        // [B, P, 4]
        const float* __restrict__ prior,      // [P, 4]
        float* __restrict__ out,              // [B, C, TOPK, 5]
        int use_transposed,
        const float* __restrict__ confT) {    // [B][C][P]
    #pragma clang fp contract(off)

    const int c = blockIdx.x;
    const int b = blockIdx.y;
    const int t = threadIdx.x;
    const long long obase = ((long long)(b * NUM_CLASSES + c)) * (TOPK * 5);

    if (c == 0) {
        // background class: reference zeroes it. d_out is poisoned -> must write.
        for (int e = t; e < TOPK * 5; e += 256) out[obase + e] = 0.0f;
        return;
    }

    __shared__ unsigned int hist[NBINS];                 // 16384 B
    __shared__ unsigned long long cand[CAP];             // 16384 B
    __shared__ unsigned long long cand2[CAP];            // 16384 B
    __shared__ float bx[TOPK][4];                        // 3200 B
    __shared__ float sc[TOPK];                           // 800 B
    __shared__ float ar[TOPK];                           // 800 B
    __shared__ unsigned long long msk[TOPK][4];          // 6400 B
    __shared__ int keepi[TOPK];                          // 800 B
    __shared__ unsigned int gsum[64];                    // 256 B
    __shared__ int s_cnt1, s_cnt2, s_tbin, s_nkeep;

    // init
    for (int i = t; i < NBINS; i += 256) hist[i] = 0u;
    if (t == 0) { s_cnt1 = 0; s_cnt2 = 0; s_nkeep = 0; }
    __syncthreads();

    const float* src;
    long long stride;
    if (use_transposed) {
        src = confT + ((long long)(b * NUM_CLASSES + c)) * P_NUM;
        stride = 1;
    } else {
        src = conf + (long long)b * P_NUM * NUM_CLASSES + c;
        stride = NUM_CLASSES;
    }

    // -------- pass 1: histogram + opportunistic prefiltered collection ------
    for (int p = t; p < P_NUM; p += 256) {
        float s = src[(long long)p * stride];
        if (s > CONF_TH) {
            int bin = (int)(s * (float)NBINS);
            bin = min(max(bin, 0), NBINS - 1);
            atomicAdd(&hist[bin], 1u);
            if (s > PRE_TH) {
                int pos = atomicAdd(&s_cnt1, 1);
                if (pos < CAP) {
                    cand[pos] = ((unsigned long long)__float_as_uint(s) << 32)
                              | (unsigned long long)(0xFFFFFFFFu - (unsigned int)p);
                }
            }
        }
    }
    __syncthreads();

    // -------- find exact threshold bin (200th largest) ----------------------
    if (t < 64) {
        unsigned int a = 0;
        for (int i = 0; i < 64; ++i) a += hist[t * 64 + i];
        gsum[t] = a;
    }
    __syncthreads();
    if (t == 0) {
        int acc = 0;
        int g = 63;
        for (; g >= 0; --g) {
            if (acc + (int)gsum[g] >= TOPK) break;
            acc += (int)gsum[g];
        }
        int tbin = 0;
        if (g >= 0) {
            int bbase = g * 64;
            for (int bi = 63; bi >= 0; --bi) {
                acc += (int)hist[bbase + bi];
                if (acc >= TOPK) { tbin = bbase + bi; break; }
            }
        }
        s_tbin = tbin;   // tbin==0 also covers "fewer than 200 above conf"
    }
    __syncthreads();

    const int tbin = s_tbin;
    const bool fastpath = (s_cnt1 <= CAP) && (tbin >= TSAFE);

    // -------- pass 2: exact candidate set {score>conf, bin >= tbin} ---------
    if (fastpath) {
        int n1 = s_cnt1;
        for (int i = t; i < n1; i += 256) {
            unsigned long long k = cand[i];
            float s = __uint_as_float((unsigned int)(k >> 32));
            int bin = (int)(s * (float)NBINS);
            bin = min(max(bin, 0), NBINS - 1);
            if (bin >= tbin) {
                int pos = atomicAdd(&s_cnt2, 1);
                if (pos < CAP) cand2[pos] = k;
            }
        }
    } else {
        for (int p = t; p < P_NUM; p += 256) {
            float s = src[(long long)p * stride];
            if (s > CONF_TH) {
                int bin = (int)(s * (float)NBINS);
                bin = min(max(bin, 0), NBINS - 1);
                if (bin >= tbin) {
                    int pos = atomicAdd(&s_cnt2, 1);
                    if (pos < CAP) {
                        cand2[pos] = ((unsigned long long)__float_as_uint(s) << 32)
                                   | (unsigned long long)(0xFFFFFFFFu - (unsigned int)p);
                    }
                }
            }
        }
    }
    __syncthreads();

    // -------- bitonic sort descending (key: score_bits desc, index asc) -----
    int n2 = min(s_cnt2, CAP);
    int N = 256;
    while (N < n2) N <<= 1;           // <= 2048
    for (int i = n2 + t; i < N; i += 256) cand2[i] = 0ULL;   // pad sorts last
    __syncthreads();
    for (int k = 2; k <= N; k <<= 1) {
        for (int j = k >> 1; j > 0; j >>= 1) {
            for (int i = t; i < N; i += 256) {
                int ixj = i ^ j;
                if (ixj > i) {
                    unsigned long long a = cand2[i], bb = cand2[ixj];
                    bool up = ((i & k) == 0);
                    if (up ? (a < bb) : (a > bb)) { cand2[i] = bb; cand2[ixj] = a; }
                }
            }
            __syncthreads();
        }
    }

    // -------- decode the selected boxes -------------------------------------
    const int nrows = min(n2, TOPK);
    if (t < nrows) {
        unsigned long long kk = cand2[t];
        float s = __uint_as_float((unsigned int)(kk >> 32));
        unsigned int p = 0xFFFFFFFFu - (unsigned int)kk;
        const float* lp = loc + ((long long)b * P_NUM + p) * 4;
        const float* pp = prior + (long long)p * 4;
        float l0 = lp[0], l1 = lp[1], l2 = lp[2], l3 = lp[3];
        float pcx = pp[0], pcy = pp[1], pw = pp[2], ph = pp[3];
        float cx = pcx + (l0 * 0.1f) * pw;
        float cy = pcy + (l1 * 0.1f) * ph;
        float w  = pw * expf(l2 * 0.2f);
        float h  = ph * expf(l3 * 0.2f);
        float x1 = cx - w * 0.5f;
        float y1 = cy - h * 0.5f;
        float x2 = x1 + w;
        float y2 = y1 + h;
        bx[t][0] = x1; bx[t][1] = y1; bx[t][2] = x2; bx[t][3] = y2;
        sc[t] = s;
        ar[t] = (x2 - x1) * (y2 - y1);
    }
    __syncthreads();

    // -------- pairwise IoU > 0.3 bitmask ------------------------------------
    int units = nrows * 4;
    for (int u = t; u < units; u += 256) {
        int i = u >> 2, w = u & 3;
        float ix1 = bx[i][0], iy1 = bx[i][1], ix2 = bx[i][2], iy2 = bx[i][3], ia = ar[i];
        unsigned long long m = 0ULL;
        int j0 = w * 64;
        int jend = min(64, nrows - j0);
        for (int jj = 0; jj < jend; ++jj) {
            int j = j0 + jj;
            float xx1 = fmaxf(ix1, bx[j][0]);
            float yy1 = fmaxf(iy1, bx[j][1]);
            float xx2 = fminf(ix2, bx[j][2]);
            float yy2 = fminf(iy2, bx[j][3]);
            float ww = fmaxf(xx2 - xx1, 0.0f);
            float hh = fmaxf(yy2 - yy1, 0.0f);
            float inter = ww * hh;
            float uni = (ar[j] - inter) + ia;     // numpy order: area_j - inter + area_i
            float iou = inter / uni;
            if (iou > NMS_TH) m |= (1ULL << jj);
        }
        msk[i][w] = m;
    }
    __syncthreads();

    // -------- greedy scan (serial, bitmask OR) ------------------------------
    if (t == 0) {
        unsigned long long s0 = 0, s1 = 0, s2 = 0, s3 = 0;
        int nk = 0;
        for (int i = 0; i < nrows; ++i) {
            unsigned long long sw = (i < 64) ? s0 : (i < 128) ? s1 : (i < 192) ? s2 : s3;
            if ((sw >> (i & 63)) & 1ULL) continue;
            keepi[nk++] = i;
            s0 |= msk[i][0]; s1 |= msk[i][1]; s2 |= msk[i][2]; s3 |= msk[i][3];
        }
        s_nkeep = nk;
    }
    __syncthreads();

    // -------- write output rows (kept in pick order, zero padded) -----------
    int nk = s_nkeep;
    for (int e = t; e < TOPK * 5; e += 256) {
        int r = e / 5, comp = e - r * 5;
        float v = 0.0f;
        if (r < nk) {
            int i = keepi[r];
            v = (comp == 0) ? sc[i] : bx[i][comp - 1];
        }
        out[obase + e] = v;
    }
}

// ---------------------------------------------------------------------------
extern "C" void kernel_launch(void* const* d_in, const int* in_sizes, int n_in,
                              void* d_out, int out_size, void* d_ws, size_t ws_size,
                              hipStream_t stream) {
    const float* loc   = (const float*)d_in[0];
    const float* conf  = (const float*)d_in[1];
    const float* prior = (const float*)d_in[2];
    float* out = (float*)d_out;

    const size_t need = (size_t)B_NUM * P_NUM * NUM_CLASSES * sizeof(float);
    const int use_t = (ws_size >= need) ? 1 : 0;
    float* confT = (float*)d_ws;

    if (use_t) {
        const int nblocks = (B_NUM * P_NUM) / TROWS;   // 960000/512 = 1875
        transpose_kernel<<<nblocks, 256, 0, stream>>>(conf, confT);
    }
    dim3 grid(NUM_CLASSES, B_NUM);
    select_nms_kernel<<<grid, 256, 0, stream>>>(conf, loc, prior, out, use_t, confT);
}